// Round 7
// baseline (317.302 us; speedup 1.0000x reference)
//
#include <hip/hip_runtime.h>

__device__ __forceinline__ float u2f(unsigned short u) {
  union { unsigned int i; float f; } v; v.i = ((unsigned)u) << 16; return v.f;
}
__device__ __forceinline__ unsigned short f2u(float f) {
  union { float f; unsigned int i; } v; v.f = f;
  unsigned int x = v.i;
  return (unsigned short)((x + 0x7fffu + ((x >> 16) & 1u)) >> 16);  // RNE bf16
}
__device__ __forceinline__ unsigned int pack2(float a, float b) {
  return (unsigned int)f2u(a) | ((unsigned int)f2u(b) << 16);
}
// accumulate 2 packed bf16 (one u32) with weight
__device__ __forceinline__ void acc2(float& a0, float& a1, unsigned int w, float wgt) {
  union { unsigned int i; float f; } lo, hi;
  lo.i = w << 16; hi.i = w & 0xffff0000u;
  a0 += wgt * lo.f; a1 += wgt * hi.f;
}
// async global->LDS 16B DMA: LDS dest = wave-uniform base + lane*16
__device__ __forceinline__ void gload16(const void* g, void* l) {
  __builtin_amdgcn_global_load_lds((const __attribute__((address_space(1))) void*)g,
                                   (__attribute__((address_space(3))) void*)l, 16, 0, 0);
}

__device__ __forceinline__ void decode_hw(const void* Hp, const void* Wp, int& H, int& W) {
  long long h = ((const int*)Hp)[0], w = ((const int*)Wp)[0];
  if (h >= 1 && h <= 16384 && w >= 1 && w <= 16384 && h * w == 16384) { H = (int)h; W = (int)w; return; }
  float fh = ((const float*)Hp)[0], fw = ((const float*)Wp)[0];
  if (fh >= 1.f && fh <= 16384.f && fw >= 1.f && fw <= 16384.f &&
      (long long)fh * (long long)fw == 16384) { H = (int)fh; W = (int)fw; return; }
  H = 128; W = 128;
}

typedef __attribute__((ext_vector_type(4))) float f32x4;
typedef __attribute__((ext_vector_type(8))) short bf16x8;

// ---------------- prep: Bt[n][k] = bf16(W[k][n]) for the 3 weight matrices ----
__launch_bounds__(256)
__global__ void prep_kernel(const float* __restrict__ Wv, const float* __restrict__ Wo,
                            const float* __restrict__ Wa, const float* __restrict__ Wout,
                            const float* __restrict__ bo, const float* __restrict__ ba,
                            unsigned short* __restrict__ Btv,
                            unsigned short* __restrict__ Btout,
                            unsigned short* __restrict__ Btol,
                            float* __restrict__ bol)
{
  const int n = blockIdx.x;
  const int k = threadIdx.x;  // 0..255 = K
  if (n < 256) {
    Btv[n * 256 + k] = f2u(Wv[k * 256 + n]);
  } else if (n < 512) {
    const int nn = n - 256;
    Btout[nn * 256 + k] = f2u(Wout[k * 256 + nn]);
  } else {
    const int nn = n - 512;  // 0..127
    float v = (nn < 64) ? Wo[k * 64 + nn] : ((nn < 96) ? Wa[k * 32 + (nn - 64)] : 0.f);
    Btol[nn * 256 + k] = f2u(v);
    if (k == 0) bol[nn] = (nn < 64) ? bo[nn] : ((nn < 96) ? ba[nn - 64] : 0.f);
  }
}

// ---------------- MFMA GEMM: C[M][ldc] = A[M][256] @ Bt^T + bias --------------
// BM x BN tile, BK=64, 4 waves; wave w owns cols [w*BN/4 ...). MF=BM/16 m-frags.
// A fp32 -> bf16 at stage time (padded LDS). B bf16 via global_load_lds into
// unpadded LDS with XOR-swizzled granules (read XORs granule with row16&7).
template<int BM, int BN, bool OUTBF16>
__launch_bounds__(256)
__global__ void mfma_gemm(const float* __restrict__ A,
                          const unsigned short* __restrict__ Bt,
                          const float* __restrict__ bias,
                          void* __restrict__ C,
                          int N, int ldc)
{
  constexpr int MF = BM / 16;   // m-frags
  constexpr int NF = BN / 64;   // n-frags per wave
  constexpr int TPR = 256 / BM; // A-stage threads per row
  constexpr int EPT = 64 / TPR; // A-stage elems per thread
  __shared__ __align__(16) unsigned short As[BM][72];  // padded (VGPR-staged)
  __shared__ __align__(16) unsigned short Bs[BN][64];  // linear (DMA-staged)
  const int tid = threadIdx.x;
  const int wid = tid >> 6, lane = tid & 63;
  const int row16 = lane & 15, kq = lane >> 4;
  const int swz = row16 & 7;
  const int m0 = blockIdx.x * BM;
  const int wn0 = wid * (BN / 4);

  f32x4 acc[MF][NF];
  const f32x4 zero4 = {0.f, 0.f, 0.f, 0.f};
  #pragma unroll
  for (int i = 0; i < MF; ++i)
    #pragma unroll
    for (int j = 0; j < NF; ++j)
      acc[i][j] = zero4;

  const int arow = tid / TPR, aq = tid % TPR;
  constexpr int NISS = BN / 32;  // B DMA issues per wave (8 rows each)

  for (int k0 = 0; k0 < 256; k0 += 64) {
    // ---- B tile via global_load_lds, pre-swizzled source ----
    #pragma unroll
    for (int j = 0; j < NISS; ++j) {
      const int rowbase = (wid * NISS + j) * 8;
      const int brow = rowbase + (lane >> 3);
      const int gsrc = (lane & 7) ^ (brow & 7);
      gload16(Bt + (size_t)brow * 256 + k0 + gsrc * 8, &Bs[rowbase][0]);
    }
    // ---- A tile fp32 -> bf16, VGPR staging ----
    #pragma unroll
    for (int g = 0; g < EPT / 16; ++g) {
      const int c0 = aq * EPT + g * 16;
      const float* ap = A + (size_t)(m0 + arow) * 256 + k0 + c0;
      float4 f0 = *(const float4*)(ap + 0);
      float4 f1 = *(const float4*)(ap + 4);
      float4 g0 = *(const float4*)(ap + 8);
      float4 g1 = *(const float4*)(ap + 12);
      uint4 u0 = make_uint4(pack2(f0.x, f0.y), pack2(f0.z, f0.w), pack2(f1.x, f1.y), pack2(f1.z, f1.w));
      uint4 u1 = make_uint4(pack2(g0.x, g0.y), pack2(g0.z, g0.w), pack2(g1.x, g1.y), pack2(g1.z, g1.w));
      *(uint4*)&As[arow][c0 + 0] = u0;
      *(uint4*)&As[arow][c0 + 8] = u1;
    }
    __syncthreads();  // drains vmcnt (gload_lds) + lgkm

    #pragma unroll
    for (int ks = 0; ks < 64; ks += 32) {
      bf16x8 af[MF], bfr[NF];
      #pragma unroll
      for (int mf = 0; mf < MF; ++mf)
        af[mf] = *(const bf16x8*)&As[mf * 16 + row16][ks + kq * 8];
      #pragma unroll
      for (int nf = 0; nf < NF; ++nf)
        bfr[nf] = *(const bf16x8*)&Bs[wn0 + nf * 16 + row16][(((ks >> 3) + kq) ^ swz) * 8];
      #pragma unroll
      for (int mf = 0; mf < MF; ++mf)
        #pragma unroll
        for (int nf = 0; nf < NF; ++nf)
          acc[mf][nf] = __builtin_amdgcn_mfma_f32_16x16x32_bf16(af[mf], bfr[nf], acc[mf][nf], 0, 0, 0);
    }
    __syncthreads();
  }

  // C/D layout: col = lane&15, row = (lane>>4)*4 + r
  #pragma unroll
  for (int nf = 0; nf < NF; ++nf) {
    const int col = wn0 + nf * 16 + row16;
    if (col < N) {
      const float bv = bias[col];
      #pragma unroll
      for (int mf = 0; mf < MF; ++mf) {
        #pragma unroll
        for (int r = 0; r < 4; ++r) {
          const int rrow = m0 + mf * 16 + kq * 4 + r;
          const float v = acc[mf][nf][r] + bv;
          if (OUTBF16) ((unsigned short*)C)[(size_t)rrow * ldc + col] = f2u(v);
          else         ((float*)C)[(size_t)rrow * ldc + col] = v;
        }
      }
    }
  }
}

// ------- Fused GEMM (sampled @ W_out + b_out) + residual(tgt) + LayerNorm ----
// BM=128, BN=256; both operands DMA-staged with swizzle.
__launch_bounds__(256)
__global__ void gemm_ln_kernel(const unsigned short* __restrict__ A,   // sampled bf16
                               const unsigned short* __restrict__ Bt,  // Btout
                               const float* __restrict__ bias,
                               const float* __restrict__ tgt,
                               const float* __restrict__ g,
                               const float* __restrict__ be,
                               float* __restrict__ out)
{
  constexpr int MF = 8;
  __shared__ __align__(16) unsigned short As[128][64];
  __shared__ __align__(16) unsigned short Bs[256][64];
  __shared__ float2 red_s[128][4];
  const int tid = threadIdx.x;
  const int wid = tid >> 6, lane = tid & 63;
  const int row16 = lane & 15, kq = lane >> 4;
  const int swz = row16 & 7;
  const int m0 = blockIdx.x * 128;
  const int wn0 = wid * 64;

  f32x4 acc[MF][4];
  const f32x4 zero4 = {0.f, 0.f, 0.f, 0.f};
  #pragma unroll
  for (int i = 0; i < MF; ++i)
    #pragma unroll
    for (int j = 0; j < 4; ++j)
      acc[i][j] = zero4;

  for (int k0 = 0; k0 < 256; k0 += 64) {
    #pragma unroll
    for (int j = 0; j < 8; ++j) {      // B: 8 issues/wave x 8 rows
      const int rowbase = (wid * 8 + j) * 8;
      const int brow = rowbase + (lane >> 3);
      const int gsrc = (lane & 7) ^ (brow & 7);
      gload16(Bt + (size_t)brow * 256 + k0 + gsrc * 8, &Bs[rowbase][0]);
    }
    #pragma unroll
    for (int j = 0; j < 4; ++j) {      // A: 4 issues/wave x 8 rows
      const int rowbase = (wid * 4 + j) * 8;
      const int arow = rowbase + (lane >> 3);
      const int gsrc = (lane & 7) ^ (arow & 7);
      gload16(A + (size_t)(m0 + arow) * 256 + k0 + gsrc * 8, &As[rowbase][0]);
    }
    __syncthreads();

    #pragma unroll
    for (int ks = 0; ks < 64; ks += 32) {
      bf16x8 af[MF], bfr[4];
      #pragma unroll
      for (int mf = 0; mf < MF; ++mf)
        af[mf] = *(const bf16x8*)&As[mf * 16 + row16][(((ks >> 3) + kq) ^ swz) * 8];
      #pragma unroll
      for (int nf = 0; nf < 4; ++nf)
        bfr[nf] = *(const bf16x8*)&Bs[wn0 + nf * 16 + row16][(((ks >> 3) + kq) ^ swz) * 8];
      #pragma unroll
      for (int mf = 0; mf < MF; ++mf)
        #pragma unroll
        for (int nf = 0; nf < 4; ++nf)
          acc[mf][nf] = __builtin_amdgcn_mfma_f32_16x16x32_bf16(af[mf], bfr[nf], acc[mf][nf], 0, 0, 0);
    }
    __syncthreads();
  }

  float bcol[4], gcol[4], becol[4];
  #pragma unroll
  for (int nf = 0; nf < 4; ++nf) {
    const int col = wn0 + nf * 16 + row16;
    bcol[nf] = bias[col]; gcol[nf] = g[col]; becol[nf] = be[col];
  }
  #pragma unroll
  for (int mf = 0; mf < MF; ++mf) {
    #pragma unroll
    for (int r = 0; r < 4; ++r) {
      const int row = mf * 16 + kq * 4 + r;
      float s = 0.f, q = 0.f;
      #pragma unroll
      for (int nf = 0; nf < 4; ++nf) {
        const int col = wn0 + nf * 16 + row16;
        float v = acc[mf][nf][r] + bcol[nf] + tgt[(size_t)(m0 + row) * 256 + col];
        acc[mf][nf][r] = v;
        s += v; q += v * v;
      }
      #pragma unroll
      for (int off = 1; off < 16; off <<= 1) {
        s += __shfl_xor(s, off);
        q += __shfl_xor(q, off);
      }
      if (row16 == 0) red_s[row][wid] = make_float2(s, q);
    }
  }
  __syncthreads();

  #pragma unroll
  for (int mf = 0; mf < MF; ++mf) {
    #pragma unroll
    for (int r = 0; r < 4; ++r) {
      const int row = mf * 16 + kq * 4 + r;
      const float2 a0 = red_s[row][0], a1 = red_s[row][1];
      const float2 a2 = red_s[row][2], a3 = red_s[row][3];
      const float s = a0.x + a1.x + a2.x + a3.x;
      const float q = a0.y + a1.y + a2.y + a3.y;
      const float mean = s * (1.f / 256.f);
      const float var = q * (1.f / 256.f) - mean * mean;
      const float rstd = rsqrtf(var + 1e-5f);
      #pragma unroll
      for (int nf = 0; nf < 4; ++nf) {
        const int col = wn0 + nf * 16 + row16;
        out[(size_t)(m0 + row) * 256 + col] = (acc[mf][nf][r] - mean) * rstd * gcol[nf] + becol[nf];
      }
    }
  }
}

// -------- Sampler: softmax + bilinear, 8 channels/thread via 16B gathers ----
#define RQ 8
__launch_bounds__(256)
__global__ void sample_kernel(const unsigned short* __restrict__ value, // (B,S,NH,DH) bf16
                              const float* __restrict__ offlog,         // (B*LQ,96) fp32
                              const float* __restrict__ refp,           // (B*LQ,2)
                              unsigned short* __restrict__ out,         // (B*LQ,256) bf16
                              const void* __restrict__ Hp,
                              const void* __restrict__ Wp)
{
  int H, W; decode_hw(Hp, Wp, H, W);
  const int S = H * W;
  __shared__ float off_s[RQ][64];
  __shared__ float lg_s[RQ][36];
  __shared__ float ref_s[RQ][2];
  const int tid = threadIdx.x;
  const int r0 = blockIdx.x * RQ;

  if (tid < RQ * 24) {
    const int row = tid / 24, c4 = (tid % 24) * 4;
    float4 v = *(const float4*)(offlog + (size_t)(r0 + row) * 96 + c4);
    if (c4 < 64) *(float4*)&off_s[row][c4] = v;
    else         *(float4*)&lg_s[row][c4 - 64] = v;
  }
  if (tid < RQ * 2)
    ref_s[tid >> 1][tid & 1] = refp[(size_t)(r0 + (tid >> 1)) * 2 + (tid & 1)];
  __syncthreads();

  const int row = tid >> 5;          // 0..7
  const int h   = (tid >> 2) & 7;    // head
  const int o   = tid & 3;           // channel octet (8 ch)
  const int b = r0 >> 13;            // LQ = 8192
  const unsigned short* vptr = value + (size_t)b * S * 256 + h * 32 + o * 8;

  const int r = r0 + row;
  float lg[4];
  #pragma unroll
  for (int p = 0; p < 4; ++p) lg[p] = lg_s[row][h * 4 + p];
  const float mx = fmaxf(fmaxf(lg[0], lg[1]), fmaxf(lg[2], lg[3]));
  float sum = 0.f;
  #pragma unroll
  for (int p = 0; p < 4; ++p) { lg[p] = __expf(lg[p] - mx); sum += lg[p]; }
  const float inv = 1.f / sum;
  const float rx = ref_s[row][0], ry = ref_s[row][1];

  float a[8];
  #pragma unroll
  for (int j = 0; j < 8; ++j) a[j] = 0.f;

  #pragma unroll
  for (int p = 0; p < 4; ++p) {
    const float x = rx * (float)W + off_s[row][h * 8 + p * 2 + 0] - 0.5f;
    const float y = ry * (float)H + off_s[row][h * 8 + p * 2 + 1] - 0.5f;
    const float xf = floorf(x), yf = floorf(y);
    const float wx = x - xf, wy = y - yf;
    const int x0 = (int)xf, y0 = (int)yf;
    const float wp = lg[p] * inv;
    #pragma unroll
    for (int dy = 0; dy < 2; ++dy)
      #pragma unroll
      for (int dx = 0; dx < 2; ++dx) {
        const int yy = y0 + dy, xx = x0 + dx;
        if ((unsigned)yy < (unsigned)H && (unsigned)xx < (unsigned)W) {
          const float wgt = wp * (dy ? wy : 1.f - wy) * (dx ? wx : 1.f - wx);
          const uint4 v4 = *(const uint4*)(vptr + (size_t)(yy * W + xx) * 256);
          acc2(a[0], a[1], v4.x, wgt);
          acc2(a[2], a[3], v4.y, wgt);
          acc2(a[4], a[5], v4.z, wgt);
          acc2(a[6], a[7], v4.w, wgt);
        }
      }
  }
  uint4 ov;
  ov.x = pack2(a[0], a[1]); ov.y = pack2(a[2], a[3]);
  ov.z = pack2(a[4], a[5]); ov.w = pack2(a[6], a[7]);
  *(uint4*)(out + (size_t)r * 256 + h * 32 + o * 8) = ov;
}

// LN(2*x): single read of src.
__launch_bounds__(256)
__global__ void ln2x_kernel(const float* __restrict__ A,
                            const float* __restrict__ g,
                            const float* __restrict__ be,
                            float* __restrict__ out)
{
  const size_t row = (size_t)blockIdx.x * 4 + (threadIdx.x >> 6);
  const int lane = threadIdx.x & 63;
  const size_t base = row * 256 + lane * 4;
  const float4 xa = *(const float4*)(A + base);
  float x[4];
  x[0] = 2.f * xa.x; x[1] = 2.f * xa.y; x[2] = 2.f * xa.z; x[3] = 2.f * xa.w;
  float s = x[0] + x[1] + x[2] + x[3];
  float sq = x[0]*x[0] + x[1]*x[1] + x[2]*x[2] + x[3]*x[3];
  #pragma unroll
  for (int off = 32; off; off >>= 1) {
    s  += __shfl_xor(s, off);
    sq += __shfl_xor(sq, off);
  }
  const float mean = s * (1.f / 256.f);
  const float var = sq * (1.f / 256.f) - mean * mean;
  const float rstd = rsqrtf(var + 1e-5f);
  const float4 gg = *(const float4*)(g + lane * 4);
  const float4 bb = *(const float4*)(be + lane * 4);
  float4 o;
  o.x = (x[0] - mean) * rstd * gg.x + bb.x;
  o.y = (x[1] - mean) * rstd * gg.y + bb.y;
  o.z = (x[2] - mean) * rstd * gg.z + bb.z;
  o.w = (x[3] - mean) * rstd * gg.w + bb.w;
  *(float4*)(out + base) = o;
}

extern "C" void kernel_launch(void* const* d_in, const int* in_sizes, int n_in,
                              void* d_out, int out_size, void* d_ws, size_t ws_size,
                              hipStream_t stream) {
  const float* tgt  = (const float*)d_in[0];
  const float* src  = (const float*)d_in[1];
  const float* refp = (const float*)d_in[2];
  const float* Wv   = (const float*)d_in[3];
  const float* bv   = (const float*)d_in[4];
  const float* Wo   = (const float*)d_in[5];
  const float* bo   = (const float*)d_in[6];
  const float* Wa   = (const float*)d_in[7];
  const float* ba   = (const float*)d_in[8];
  const float* Wout = (const float*)d_in[9];
  const float* bout = (const float*)d_in[10];
  const float* g1   = (const float*)d_in[11];
  const float* b1   = (const float*)d_in[12];
  const float* g2   = (const float*)d_in[13];
  const float* b2   = (const float*)d_in[14];
  const void* Hp    = d_in[15];
  const void* Wp    = d_in[16];

  // d_out: fp32, [query 8388608 | src_out 16777216] elements.
  float* q_out    = (float*)d_out;
  float* s_region = q_out + (size_t)8388608;
  float* s_out    = s_region;

  // ws layout: value bf16 [65536*256] (33.55 MB) + Bt matrices + bol
  unsigned short* value = (unsigned short*)d_ws;
  unsigned short* Btv   = value + (size_t)16777216;
  unsigned short* Btout = Btv + 65536;
  unsigned short* Btol  = Btout + 65536;
  float*          bol   = (float*)(Btol + 32768);

  // s_region (67 MB, dead until ln2x at the end):
  //   offlog fp32 [32768][96]  : floats [0, 3145728)
  //   sampled bf16 [32768][256]: floats [4194304, 8388608)
  float*          offlog  = s_region;
  unsigned short* sampled = (unsigned short*)(s_region + (size_t)4194304);

  dim3 blk(256);
  // 0. weight transpose/convert -> bf16 Bt[n][k]
  prep_kernel<<<dim3(640), blk, 0, stream>>>(Wv, Wo, Wa, Wout, bo, ba, Btv, Btout, Btol, bol);
  // 1. offlog = tgt @ [W_off|W_attn] + bias   (32768 x 96 x 256, MFMA, BM=128)
  mfma_gemm<128, 128, false><<<dim3(256), blk, 0, stream>>>(tgt, Btol, bol, offlog, 96, 96);
  // 2. value = src @ W_value + b_value        (65536 x 256 x 256, MFMA, BM=128) -> bf16
  mfma_gemm<128, 256, true><<<dim3(512), blk, 0, stream>>>(src, Btv, bv, value, 256, 256);
  // 3. softmax + bilinear sampling -> sampled bf16
  sample_kernel<<<dim3(32768 / RQ), blk, 0, stream>>>(value, offlog, refp, sampled, Hp, Wp);
  // 4. query = LN(tgt + sampled @ W_out + b_out) -> q_out  (fused GEMM+LN, BM=128)
  gemm_ln_kernel<<<dim3(256), blk, 0, stream>>>(sampled, Btout, bout, tgt, g1, b1, q_out);
  // 5. src_out = LN(2*src) -> s_out (overwrites dead offlog/sampled)
  ln2x_kernel<<<dim3(16384), blk, 0, stream>>>(src, g2, b2, s_out);
}

// Round 8
// 288.003 us; speedup vs baseline: 1.1017x; 1.1017x over previous
//
#include <hip/hip_runtime.h>

__device__ __forceinline__ float u2f(unsigned short u) {
  union { unsigned int i; float f; } v; v.i = ((unsigned)u) << 16; return v.f;
}
__device__ __forceinline__ unsigned short f2u(float f) {
  union { float f; unsigned int i; } v; v.f = f;
  unsigned int x = v.i;
  return (unsigned short)((x + 0x7fffu + ((x >> 16) & 1u)) >> 16);  // RNE bf16
}
__device__ __forceinline__ unsigned int pack2(float a, float b) {
  return (unsigned int)f2u(a) | ((unsigned int)f2u(b) << 16);
}
// accumulate 2 packed bf16 (one u32) with weight
__device__ __forceinline__ void acc2(float& a0, float& a1, unsigned int w, float wgt) {
  union { unsigned int i; float f; } lo, hi;
  lo.i = w << 16; hi.i = w & 0xffff0000u;
  a0 += wgt * lo.f; a1 += wgt * hi.f;
}
// async global->LDS 16B DMA: LDS dest = wave-uniform base + lane*16
__device__ __forceinline__ void gload16(const void* g, void* l) {
  __builtin_amdgcn_global_load_lds((const __attribute__((address_space(1))) void*)g,
                                   (__attribute__((address_space(3))) void*)l, 16, 0, 0);
}

__device__ __forceinline__ void decode_hw(const void* Hp, const void* Wp, int& H, int& W) {
  long long h = ((const int*)Hp)[0], w = ((const int*)Wp)[0];
  if (h >= 1 && h <= 16384 && w >= 1 && w <= 16384 && h * w == 16384) { H = (int)h; W = (int)w; return; }
  float fh = ((const float*)Hp)[0], fw = ((const float*)Wp)[0];
  if (fh >= 1.f && fh <= 16384.f && fw >= 1.f && fw <= 16384.f &&
      (long long)fh * (long long)fw == 16384) { H = (int)fh; W = (int)fw; return; }
  H = 128; W = 128;
}

typedef __attribute__((ext_vector_type(4))) float f32x4;
typedef __attribute__((ext_vector_type(8))) short bf16x8;

// ---------------- prep: Bt[n][k] = bf16(W[k][n]) for the 3 weight matrices ----
__launch_bounds__(256)
__global__ void prep_kernel(const float* __restrict__ Wv, const float* __restrict__ Wo,
                            const float* __restrict__ Wa, const float* __restrict__ Wout,
                            const float* __restrict__ bo, const float* __restrict__ ba,
                            unsigned short* __restrict__ Btv,
                            unsigned short* __restrict__ Btout,
                            unsigned short* __restrict__ Btol,
                            float* __restrict__ bol)
{
  const int n = blockIdx.x;
  const int k = threadIdx.x;  // 0..255 = K
  if (n < 256) {
    Btv[n * 256 + k] = f2u(Wv[k * 256 + n]);
  } else if (n < 512) {
    const int nn = n - 256;
    Btout[nn * 256 + k] = f2u(Wout[k * 256 + nn]);
  } else {
    const int nn = n - 512;  // 0..127
    float v = (nn < 64) ? Wo[k * 64 + nn] : ((nn < 96) ? Wa[k * 32 + (nn - 64)] : 0.f);
    Btol[nn * 256 + k] = f2u(v);
    if (k == 0) bol[nn] = (nn < 64) ? bo[nn] : ((nn < 96) ? ba[nn - 64] : 0.f);
  }
}

// ---------------- MFMA GEMM: C[M][ldc] = A[M][256] @ Bt^T + bias --------------
// BM=64, BK=64, 4 waves. A fp32 -> bf16, VGPR-staged with REGISTER PREFETCH of
// the next K-chunk (raw-asm counted barriers keep the prefetch in flight across
// the barrier -- vmcnt(4) not vmcnt(0)). B bf16 via global_load_lds, unpadded
// LDS, XOR-swizzled granules. OUTBF16: LDS-staged coalesced epilogue (16B/lane).
template<int BN, bool OUTBF16>
__launch_bounds__(256)
__global__ void mfma_gemm(const float* __restrict__ A,
                          const unsigned short* __restrict__ Bt,
                          const float* __restrict__ bias,
                          void* __restrict__ C,
                          int N, int ldc)
{
  constexpr int NF = BN / 64;    // n-frags per wave
  constexpr int NISS = BN / 32;  // B DMA issues per wave (8 rows each)
  __shared__ __align__(16) unsigned short smem[BN * 64 + 64 * 72];
  unsigned short (*Bs)[64] = (unsigned short(*)[64])smem;            // linear, DMA
  unsigned short (*As)[72] = (unsigned short(*)[72])(smem + BN * 64); // padded
  const int tid = threadIdx.x;
  const int wid = tid >> 6, lane = tid & 63;
  const int row16 = lane & 15, kq = lane >> 4;
  const int swz = row16 & 7;
  const int m0 = blockIdx.x * 64;
  const int wn0 = wid * (BN / 4);

  f32x4 acc[4][NF];
  const f32x4 zero4 = {0.f, 0.f, 0.f, 0.f};
  #pragma unroll
  for (int i = 0; i < 4; ++i)
    #pragma unroll
    for (int j = 0; j < NF; ++j)
      acc[i][j] = zero4;

  const int arow = tid >> 2, aq = tid & 3;  // A-stage: 16 floats per thread
  const float* arp = A + (size_t)(m0 + arow) * 256 + aq * 16;

  float4 pf0, pf1, pf2, pf3;
  // ---- prologue: load A(0), issue B(0), write A(0), prefetch A(1) ----
  pf0 = *(const float4*)(arp + 0);  pf1 = *(const float4*)(arp + 4);
  pf2 = *(const float4*)(arp + 8);  pf3 = *(const float4*)(arp + 12);
  #pragma unroll
  for (int j = 0; j < NISS; ++j) {
    const int rowbase = (wid * NISS + j) * 8;
    const int brow = rowbase + (lane >> 3);
    const int gsrc = (lane & 7) ^ (brow & 7);
    gload16(Bt + (size_t)brow * 256 + 0 + gsrc * 8, &Bs[rowbase][0]);
  }
  {
    uint4 u0 = make_uint4(pack2(pf0.x, pf0.y), pack2(pf0.z, pf0.w), pack2(pf1.x, pf1.y), pack2(pf1.z, pf1.w));
    uint4 u1 = make_uint4(pack2(pf2.x, pf2.y), pack2(pf2.z, pf2.w), pack2(pf3.x, pf3.y), pack2(pf3.z, pf3.w));
    *(uint4*)&As[arow][aq * 16 + 0] = u0;
    *(uint4*)&As[arow][aq * 16 + 8] = u1;
  }
  pf0 = *(const float4*)(arp + 64); pf1 = *(const float4*)(arp + 68);
  pf2 = *(const float4*)(arp + 72); pf3 = *(const float4*)(arp + 76);
  asm volatile("s_waitcnt vmcnt(4) lgkmcnt(0)\n\ts_barrier" ::: "memory");

  #pragma unroll
  for (int c = 0; c < 4; ++c) {
    // ---- compute chunk c ----
    #pragma unroll
    for (int ks = 0; ks < 64; ks += 32) {
      bf16x8 af[4], bfr[NF];
      #pragma unroll
      for (int mf = 0; mf < 4; ++mf)
        af[mf] = *(const bf16x8*)&As[mf * 16 + row16][ks + kq * 8];
      #pragma unroll
      for (int nf = 0; nf < NF; ++nf)
        bfr[nf] = *(const bf16x8*)&Bs[wn0 + nf * 16 + row16][(((ks >> 3) + kq) ^ swz) * 8];
      #pragma unroll
      for (int mf = 0; mf < 4; ++mf)
        #pragma unroll
        for (int nf = 0; nf < NF; ++nf)
          acc[mf][nf] = __builtin_amdgcn_mfma_f32_16x16x32_bf16(af[mf], bfr[nf], acc[mf][nf], 0, 0, 0);
    }
    if (c < 3) {
      const int k1 = (c + 1) * 64;
      // WAR barrier: no vm drain (A-prefetch stays in flight)
      asm volatile("s_barrier" ::: "memory");
      #pragma unroll
      for (int j = 0; j < NISS; ++j) {
        const int rowbase = (wid * NISS + j) * 8;
        const int brow = rowbase + (lane >> 3);
        const int gsrc = (lane & 7) ^ (brow & 7);
        gload16(Bt + (size_t)brow * 256 + k1 + gsrc * 8, &Bs[rowbase][0]);
      }
      {
        uint4 u0 = make_uint4(pack2(pf0.x, pf0.y), pack2(pf0.z, pf0.w), pack2(pf1.x, pf1.y), pack2(pf1.z, pf1.w));
        uint4 u1 = make_uint4(pack2(pf2.x, pf2.y), pack2(pf2.z, pf2.w), pack2(pf3.x, pf3.y), pack2(pf3.z, pf3.w));
        *(uint4*)&As[arow][aq * 16 + 0] = u0;
        *(uint4*)&As[arow][aq * 16 + 8] = u1;
      }
      if (c < 2) {
        const float* apn = arp + (c + 2) * 64;
        pf0 = *(const float4*)(apn + 0);  pf1 = *(const float4*)(apn + 4);
        pf2 = *(const float4*)(apn + 8);  pf3 = *(const float4*)(apn + 12);
        asm volatile("s_waitcnt vmcnt(4) lgkmcnt(0)\n\ts_barrier" ::: "memory");
      } else {
        asm volatile("s_waitcnt vmcnt(0) lgkmcnt(0)\n\ts_barrier" ::: "memory");
      }
    }
  }

  // ---- epilogue ----
  if constexpr (OUTBF16) {
    // stage C-tile (bias added) into LDS, then coalesced 16B/lane stores
    asm volatile("s_barrier" ::: "memory");  // WAR: smem reuse
    unsigned short (*Cs)[264] = (unsigned short(*)[264])smem;  // 64x264 <= smem
    #pragma unroll
    for (int nf = 0; nf < NF; ++nf) {
      const int col = wn0 + nf * 16 + row16;
      const float bv = bias[col];
      #pragma unroll
      for (int mf = 0; mf < 4; ++mf)
        #pragma unroll
        for (int r = 0; r < 4; ++r)
          Cs[mf * 16 + kq * 4 + r][col] = f2u(acc[mf][nf][r] + bv);
    }
    asm volatile("s_waitcnt lgkmcnt(0)\n\ts_barrier" ::: "memory");
    #pragma unroll
    for (int j = 0; j < 8; ++j) {
      const int row = j * 8 + (tid >> 5);
      const int col = (tid & 31) * 8;
      *(uint4*)((unsigned short*)C + (size_t)(m0 + row) * ldc + col) = *(const uint4*)&Cs[row][col];
    }
  } else {
    #pragma unroll
    for (int nf = 0; nf < NF; ++nf) {
      const int col = wn0 + nf * 16 + row16;
      if (col < N) {
        const float bv = bias[col];
        #pragma unroll
        for (int mf = 0; mf < 4; ++mf)
          #pragma unroll
          for (int r = 0; r < 4; ++r)
            ((float*)C)[(size_t)(m0 + mf * 16 + kq * 4 + r) * ldc + col] = acc[mf][nf][r] + bv;
      }
    }
  }
}

// ------- Fused GEMM (sampled @ W_out + b_out) + residual(tgt) + LayerNorm ----
// BM=64, BN=256; both operands DMA-staged with swizzle (R6-proven).
__launch_bounds__(256)
__global__ void gemm_ln_kernel(const unsigned short* __restrict__ A,   // sampled bf16
                               const unsigned short* __restrict__ Bt,  // Btout
                               const float* __restrict__ bias,
                               const float* __restrict__ tgt,
                               const float* __restrict__ g,
                               const float* __restrict__ be,
                               float* __restrict__ out)
{
  __shared__ __align__(16) unsigned short As[64][64];
  __shared__ __align__(16) unsigned short Bs[256][64];
  __shared__ float2 red_s[64][4];
  const int tid = threadIdx.x;
  const int wid = tid >> 6, lane = tid & 63;
  const int row16 = lane & 15, kq = lane >> 4;
  const int swz = row16 & 7;
  const int m0 = blockIdx.x * 64;
  const int wn0 = wid * 64;

  f32x4 acc[4][4];
  const f32x4 zero4 = {0.f, 0.f, 0.f, 0.f};
  #pragma unroll
  for (int i = 0; i < 4; ++i)
    #pragma unroll
    for (int j = 0; j < 4; ++j)
      acc[i][j] = zero4;

  for (int k0 = 0; k0 < 256; k0 += 64) {
    #pragma unroll
    for (int j = 0; j < 8; ++j) {      // B: 8 issues/wave x 8 rows
      const int rowbase = (wid * 8 + j) * 8;
      const int brow = rowbase + (lane >> 3);
      const int gsrc = (lane & 7) ^ (brow & 7);
      gload16(Bt + (size_t)brow * 256 + k0 + gsrc * 8, &Bs[rowbase][0]);
    }
    #pragma unroll
    for (int j = 0; j < 2; ++j) {      // A: 2 issues/wave x 8 rows
      const int rowbase = (wid * 2 + j) * 8;
      const int arow = rowbase + (lane >> 3);
      const int gsrc = (lane & 7) ^ (arow & 7);
      gload16(A + (size_t)(m0 + arow) * 256 + k0 + gsrc * 8, &As[rowbase][0]);
    }
    __syncthreads();

    #pragma unroll
    for (int ks = 0; ks < 64; ks += 32) {
      bf16x8 af[4], bfr[4];
      #pragma unroll
      for (int mf = 0; mf < 4; ++mf)
        af[mf] = *(const bf16x8*)&As[mf * 16 + row16][(((ks >> 3) + kq) ^ swz) * 8];
      #pragma unroll
      for (int nf = 0; nf < 4; ++nf)
        bfr[nf] = *(const bf16x8*)&Bs[wn0 + nf * 16 + row16][(((ks >> 3) + kq) ^ swz) * 8];
      #pragma unroll
      for (int mf = 0; mf < 4; ++mf)
        #pragma unroll
        for (int nf = 0; nf < 4; ++nf)
          acc[mf][nf] = __builtin_amdgcn_mfma_f32_16x16x32_bf16(af[mf], bfr[nf], acc[mf][nf], 0, 0, 0);
    }
    __syncthreads();
  }

  float bcol[4], gcol[4], becol[4];
  #pragma unroll
  for (int nf = 0; nf < 4; ++nf) {
    const int col = wn0 + nf * 16 + row16;
    bcol[nf] = bias[col]; gcol[nf] = g[col]; becol[nf] = be[col];
  }
  #pragma unroll
  for (int mf = 0; mf < 4; ++mf) {
    #pragma unroll
    for (int r = 0; r < 4; ++r) {
      const int row = mf * 16 + kq * 4 + r;
      float s = 0.f, q = 0.f;
      #pragma unroll
      for (int nf = 0; nf < 4; ++nf) {
        const int col = wn0 + nf * 16 + row16;
        float v = acc[mf][nf][r] + bcol[nf] + tgt[(size_t)(m0 + row) * 256 + col];
        acc[mf][nf][r] = v;
        s += v; q += v * v;
      }
      #pragma unroll
      for (int off = 1; off < 16; off <<= 1) {
        s += __shfl_xor(s, off);
        q += __shfl_xor(q, off);
      }
      if (row16 == 0) red_s[row][wid] = make_float2(s, q);
    }
  }
  __syncthreads();

  #pragma unroll
  for (int mf = 0; mf < 4; ++mf) {
    #pragma unroll
    for (int r = 0; r < 4; ++r) {
      const int row = mf * 16 + kq * 4 + r;
      const float2 a0 = red_s[row][0], a1 = red_s[row][1];
      const float2 a2 = red_s[row][2], a3 = red_s[row][3];
      const float s = a0.x + a1.x + a2.x + a3.x;
      const float q = a0.y + a1.y + a2.y + a3.y;
      const float mean = s * (1.f / 256.f);
      const float var = q * (1.f / 256.f) - mean * mean;
      const float rstd = rsqrtf(var + 1e-5f);
      #pragma unroll
      for (int nf = 0; nf < 4; ++nf) {
        const int col = wn0 + nf * 16 + row16;
        out[(size_t)(m0 + row) * 256 + col] = (acc[mf][nf][r] - mean) * rstd * gcol[nf] + becol[nf];
      }
    }
  }
}

// -------- Sampler: softmax + bilinear, 8 channels/thread via 16B gathers ----
#define RQ 8
__launch_bounds__(256)
__global__ void sample_kernel(const unsigned short* __restrict__ value, // (B,S,NH,DH) bf16
                              const float* __restrict__ offlog,         // (B*LQ,96) fp32
                              const float* __restrict__ refp,           // (B*LQ,2)
                              unsigned short* __restrict__ out,         // (B*LQ,256) bf16
                              const void* __restrict__ Hp,
                              const void* __restrict__ Wp)
{
  int H, W; decode_hw(Hp, Wp, H, W);
  const int S = H * W;
  __shared__ float off_s[RQ][64];
  __shared__ float lg_s[RQ][36];
  __shared__ float ref_s[RQ][2];
  const int tid = threadIdx.x;
  const int r0 = blockIdx.x * RQ;

  if (tid < RQ * 24) {
    const int row = tid / 24, c4 = (tid % 24) * 4;
    float4 v = *(const float4*)(offlog + (size_t)(r0 + row) * 96 + c4);
    if (c4 < 64) *(float4*)&off_s[row][c4] = v;
    else         *(float4*)&lg_s[row][c4 - 64] = v;
  }
  if (tid < RQ * 2)
    ref_s[tid >> 1][tid & 1] = refp[(size_t)(r0 + (tid >> 1)) * 2 + (tid & 1)];
  __syncthreads();

  const int row = tid >> 5;          // 0..7
  const int h   = (tid >> 2) & 7;    // head
  const int o   = tid & 3;           // channel octet (8 ch)
  const int b = r0 >> 13;            // LQ = 8192
  const unsigned short* vptr = value + (size_t)b * S * 256 + h * 32 + o * 8;

  const int r = r0 + row;
  float lg[4];
  #pragma unroll
  for (int p = 0; p < 4; ++p) lg[p] = lg_s[row][h * 4 + p];
  const float mx = fmaxf(fmaxf(lg[0], lg[1]), fmaxf(lg[2], lg[3]));
  float sum = 0.f;
  #pragma unroll
  for (int p = 0; p < 4; ++p) { lg[p] = __expf(lg[p] - mx); sum += lg[p]; }
  const float inv = 1.f / sum;
  const float rx = ref_s[row][0], ry = ref_s[row][1];

  float a[8];
  #pragma unroll
  for (int j = 0; j < 8; ++j) a[j] = 0.f;

  #pragma unroll
  for (int p = 0; p < 4; ++p) {
    const float x = rx * (float)W + off_s[row][h * 8 + p * 2 + 0] - 0.5f;
    const float y = ry * (float)H + off_s[row][h * 8 + p * 2 + 1] - 0.5f;
    const float xf = floorf(x), yf = floorf(y);
    const float wx = x - xf, wy = y - yf;
    const int x0 = (int)xf, y0 = (int)yf;
    const float wp = lg[p] * inv;
    #pragma unroll
    for (int dy = 0; dy < 2; ++dy)
      #pragma unroll
      for (int dx = 0; dx < 2; ++dx) {
        const int yy = y0 + dy, xx = x0 + dx;
        if ((unsigned)yy < (unsigned)H && (unsigned)xx < (unsigned)W) {
          const float wgt = wp * (dy ? wy : 1.f - wy) * (dx ? wx : 1.f - wx);
          const uint4 v4 = *(const uint4*)(vptr + (size_t)(yy * W + xx) * 256);
          acc2(a[0], a[1], v4.x, wgt);
          acc2(a[2], a[3], v4.y, wgt);
          acc2(a[4], a[5], v4.z, wgt);
          acc2(a[6], a[7], v4.w, wgt);
        }
      }
  }
  uint4 ov;
  ov.x = pack2(a[0], a[1]); ov.y = pack2(a[2], a[3]);
  ov.z = pack2(a[4], a[5]); ov.w = pack2(a[6], a[7]);
  *(uint4*)(out + (size_t)r * 256 + h * 32 + o * 8) = ov;
}

// LN(2*x): single read of src.
__launch_bounds__(256)
__global__ void ln2x_kernel(const float* __restrict__ A,
                            const float* __restrict__ g,
                            const float* __restrict__ be,
                            float* __restrict__ out)
{
  const size_t row = (size_t)blockIdx.x * 4 + (threadIdx.x >> 6);
  const int lane = threadIdx.x & 63;
  const size_t base = row * 256 + lane * 4;
  const float4 xa = *(const float4*)(A + base);
  float x[4];
  x[0] = 2.f * xa.x; x[1] = 2.f * xa.y; x[2] = 2.f * xa.z; x[3] = 2.f * xa.w;
  float s = x[0] + x[1] + x[2] + x[3];
  float sq = x[0]*x[0] + x[1]*x[1] + x[2]*x[2] + x[3]*x[3];
  #pragma unroll
  for (int off = 32; off; off >>= 1) {
    s  += __shfl_xor(s, off);
    sq += __shfl_xor(sq, off);
  }
  const float mean = s * (1.f / 256.f);
  const float var = sq * (1.f / 256.f) - mean * mean;
  const float rstd = rsqrtf(var + 1e-5f);
  const float4 gg = *(const float4*)(g + lane * 4);
  const float4 bb = *(const float4*)(be + lane * 4);
  float4 o;
  o.x = (x[0] - mean) * rstd * gg.x + bb.x;
  o.y = (x[1] - mean) * rstd * gg.y + bb.y;
  o.z = (x[2] - mean) * rstd * gg.z + bb.z;
  o.w = (x[3] - mean) * rstd * gg.w + bb.w;
  *(float4*)(out + base) = o;
}

extern "C" void kernel_launch(void* const* d_in, const int* in_sizes, int n_in,
                              void* d_out, int out_size, void* d_ws, size_t ws_size,
                              hipStream_t stream) {
  const float* tgt  = (const float*)d_in[0];
  const float* src  = (const float*)d_in[1];
  const float* refp = (const float*)d_in[2];
  const float* Wv   = (const float*)d_in[3];
  const float* bv   = (const float*)d_in[4];
  const float* Wo   = (const float*)d_in[5];
  const float* bo   = (const float*)d_in[6];
  const float* Wa   = (const float*)d_in[7];
  const float* ba   = (const float*)d_in[8];
  const float* Wout = (const float*)d_in[9];
  const float* bout = (const float*)d_in[10];
  const float* g1   = (const float*)d_in[11];
  const float* b1   = (const float*)d_in[12];
  const float* g2   = (const float*)d_in[13];
  const float* b2   = (const float*)d_in[14];
  const void* Hp    = d_in[15];
  const void* Wp    = d_in[16];

  // d_out: fp32, [query 8388608 | src_out 16777216] elements.
  float* q_out    = (float*)d_out;
  float* s_region = q_out + (size_t)8388608;
  float* s_out    = s_region;

  // ws layout: value bf16 [65536*256] (33.55 MB) + Bt matrices + bol
  unsigned short* value = (unsigned short*)d_ws;
  unsigned short* Btv   = value + (size_t)16777216;
  unsigned short* Btout = Btv + 65536;
  unsigned short* Btol  = Btout + 65536;
  float*          bol   = (float*)(Btol + 32768);

  // s_region (67 MB, dead until ln2x at the end):
  //   offlog fp32 [32768][96]  : floats [0, 3145728)
  //   sampled bf16 [32768][256]: floats [4194304, 8388608)
  float*          offlog  = s_region;
  unsigned short* sampled = (unsigned short*)(s_region + (size_t)4194304);

  dim3 blk(256);
  // 0. weight transpose/convert -> bf16 Bt[n][k]
  prep_kernel<<<dim3(640), blk, 0, stream>>>(Wv, Wo, Wa, Wout, bo, ba, Btv, Btout, Btol, bol);
  // 1. offlog = tgt @ [W_off|W_attn] + bias   (32768 x 96 x 256, MFMA)
  mfma_gemm<128, false><<<dim3(512), blk, 0, stream>>>(tgt, Btol, bol, offlog, 96, 96);
  // 2. value = src @ W_value + b_value        (65536 x 256 x 256, MFMA) -> bf16
  mfma_gemm<256, true><<<dim3(1024), blk, 0, stream>>>(src, Btv, bv, value, 256, 256);
  // 3. softmax + bilinear sampling -> sampled bf16
  sample_kernel<<<dim3(32768 / RQ), blk, 0, stream>>>(value, offlog, refp, sampled, Hp, Wp);
  // 4. query = LN(tgt + sampled @ W_out + b_out) -> q_out  (fused GEMM+LN)
  gemm_ln_kernel<<<dim3(512), blk, 0, stream>>>(sampled, Btout, bout, tgt, g1, b1, q_out);
  // 5. src_out = LN(2*src) -> s_out (overwrites dead offlog/sampled)
  ln2x_kernel<<<dim3(16384), blk, 0, stream>>>(src, g2, b2, s_out);
}